// Round 2
// baseline (1862.970 us; speedup 1.0000x reference)
//
#include <hip/hip_runtime.h>
#include <math.h>

#define NNODES 100000
#define NEDGES 1200000
#define HD 64
#define NLAYERS 8
#define NGRAPH 100

// ---------- order-preserving float<->uint encoding for atomicMax ----------
__device__ __forceinline__ unsigned enc_f(float f) {
    unsigned b = __float_as_uint(f);
    return (b & 0x80000000u) ? ~b : (b | 0x80000000u);
}
__device__ __forceinline__ float dec_f(unsigned u) {
    unsigned b = (u & 0x80000000u) ? (u ^ 0x80000000u) : ~u;
    return __uint_as_float(b);
}
// sentinel = enc(-inf) = 0x007FFFFF

// ---------- lin0: x0 = relu(pos @ lin0_w + lin0_b) ----------
__global__ void lin0_k(const float* __restrict__ pos, const float* __restrict__ w,
                       const float* __restrict__ b, float* __restrict__ x0, int total) {
    int i = blockIdx.x * blockDim.x + threadIdx.x;
    if (i >= total) return;
    int n = i >> 6, h = i & 63;
    float p0 = pos[n * 3 + 0], p1 = pos[n * 3 + 1], p2 = pos[n * 3 + 2];
    float v = fmaf(p0, w[h], fmaf(p1, w[64 + h], fmaf(p2, w[128 + h], b[h])));
    x0[i] = fmaxf(v, 0.0f);
}

// ---------- CSR build ----------
__global__ void hist_k(const int* __restrict__ dst, int* __restrict__ deg, int E) {
    int e = blockIdx.x * blockDim.x + threadIdx.x;
    if (e < E) atomicAdd(&deg[dst[e]], 1);
}

__global__ void scan_part_k(const int* __restrict__ deg, int* __restrict__ bsum, int n) {
    __shared__ int s[256];
    int t = threadIdx.x;
    int i = blockIdx.x * 256 + t;
    s[t] = (i < n) ? deg[i] : 0;
    __syncthreads();
    for (int off = 128; off > 0; off >>= 1) {
        if (t < off) s[t] += s[t + off];
        __syncthreads();
    }
    if (t == 0) bsum[blockIdx.x] = s[0];
}

__global__ void scan_mid_k(const int* __restrict__ bsum, int* __restrict__ boff,
                           int nblk, int* __restrict__ roff, int n) {
    __shared__ int s[512];
    int t = threadIdx.x;
    int v = (t < nblk) ? bsum[t] : 0;
    s[t] = v;
    __syncthreads();
    for (int off = 1; off < 512; off <<= 1) {
        int u = (t >= off) ? s[t - off] : 0;
        __syncthreads();
        s[t] += u;
        __syncthreads();
    }
    if (t < nblk) boff[t] = s[t] - v;          // exclusive
    if (t == nblk - 1) roff[n] = s[t];         // == E
}

__global__ void scan_final_k(const int* __restrict__ deg, const int* __restrict__ boff,
                             int* __restrict__ roff, int n) {
    __shared__ int s[256];
    int t = threadIdx.x;
    int i = blockIdx.x * 256 + t;
    int v = (i < n) ? deg[i] : 0;
    s[t] = v;
    __syncthreads();
    for (int off = 1; off < 256; off <<= 1) {
        int u = (t >= off) ? s[t - off] : 0;
        __syncthreads();
        s[t] += u;
        __syncthreads();
    }
    if (i < n) roff[i] = boff[blockIdx.x] + s[t] - v;   // exclusive scan
}

__global__ void fill_k(const int* __restrict__ src, const int* __restrict__ dst,
                       const int* __restrict__ roff, int* __restrict__ cursor,
                       int* __restrict__ csr, int E) {
    int e = blockIdx.x * blockDim.x + threadIdx.x;
    if (e < E) {
        int d = dst[e];
        int k = atomicAdd(&cursor[d], 1);
        csr[roff[d] + k] = src[e];
    }
}

__global__ void init_pool_k(unsigned* __restrict__ pooled, int total) {
    int i = blockIdx.x * blockDim.x + threadIdx.x;
    if (i < total) pooled[i] = 0x007FFFFFu;   // enc(-inf)
}

// ---------- fused GCN2 layer: agg + residual + GEMM + relu ----------
// One wave per node. Folded matrix M = (1-beta)*I + beta*W held column-wise
// in 64 VGPRs per lane. h-row exchanged via per-wave LDS slot, read back as
// broadcast float4. 4 independent accumulators break fmaf dep chains.
__global__ __launch_bounds__(256, 8) void layer_k(
    const float* __restrict__ xin, float* __restrict__ xout,
    const float* __restrict__ x0, const float* __restrict__ W,
    const int* __restrict__ roff, const int* __restrict__ csr,
    float beta, int total_waves) {
    __shared__ __align__(16) float hrow[4][64];
    const int lane  = threadIdx.x & 63;
    const int wslot = threadIdx.x >> 6;
    const int wid0  = (blockIdx.x * blockDim.x + threadIdx.x) >> 6;
    float wcol[64];
#pragma unroll
    for (int k = 0; k < 64; ++k) {
        float w = beta * W[k * 64 + lane];
        if (k == lane) w += 1.0f - beta;      // static index: stays in VGPRs
        wcol[k] = w;
    }
    for (int n = wid0; n < NNODES; n += total_waves) {
        const int beg = roff[n], end = roff[n + 1];
        float x0v = x0[(n << 6) + lane];      // issue early, overlaps gather
        float s0 = 0.0f, s1 = 0.0f, s2 = 0.0f, s3 = 0.0f;
        int i = beg;
        for (; i + 8 <= end; i += 8) {
            int e0 = csr[i + 0], e1 = csr[i + 1], e2 = csr[i + 2], e3 = csr[i + 3];
            int e4 = csr[i + 4], e5 = csr[i + 5], e6 = csr[i + 6], e7 = csr[i + 7];
            float a0 = xin[(e0 << 6) + lane];
            float a1 = xin[(e1 << 6) + lane];
            float a2 = xin[(e2 << 6) + lane];
            float a3 = xin[(e3 << 6) + lane];
            float a4 = xin[(e4 << 6) + lane];
            float a5 = xin[(e5 << 6) + lane];
            float a6 = xin[(e6 << 6) + lane];
            float a7 = xin[(e7 << 6) + lane];
            s0 += a0; s1 += a1; s2 += a2; s3 += a3;
            s0 += a4; s1 += a5; s2 += a6; s3 += a7;
        }
        for (; i + 2 <= end; i += 2) {
            int e0 = csr[i + 0], e1 = csr[i + 1];
            s0 += xin[(e0 << 6) + lane];
            s1 += xin[(e1 << 6) + lane];
        }
        if (i < end) s2 += xin[(csr[i] << 6) + lane];
        float agg = (s0 + s1) + (s2 + s3);
        float h = fmaf(0.9f, agg, 0.1f * x0v);
        hrow[wslot][lane] = h;
        __builtin_amdgcn_wave_barrier();   // wave-internal LDS RAW; DS in-order per wave
        float a0 = 0.0f, a1 = 0.0f, a2 = 0.0f, a3 = 0.0f;
#pragma unroll
        for (int g = 0; g < 16; ++g) {
            float4 hv = *(const float4*)&hrow[wslot][g * 4];
            a0 = fmaf(hv.x, wcol[4 * g + 0], a0);
            a1 = fmaf(hv.y, wcol[4 * g + 1], a1);
            a2 = fmaf(hv.z, wcol[4 * g + 2], a2);
            a3 = fmaf(hv.w, wcol[4 * g + 3], a3);
        }
        __builtin_amdgcn_wave_barrier();   // keep next iter's write after these reads
        float o = (a0 + a1) + (a2 + a3);
        xout[(n << 6) + lane] = fmaxf(o, 0.0f);
    }
}

// ---------- lin1 + segment_max pooling fused ----------
__global__ __launch_bounds__(256, 8) void lin1pool_k(
    const float* __restrict__ xin, const float* __restrict__ W,
    const float* __restrict__ bvec, const int* __restrict__ batch,
    unsigned* __restrict__ pooled, int total_waves) {
    __shared__ __align__(16) float hrow[4][64];
    const int lane  = threadIdx.x & 63;
    const int wslot = threadIdx.x >> 6;
    const int wid0  = (blockIdx.x * blockDim.x + threadIdx.x) >> 6;
    float wcol[64];
#pragma unroll
    for (int k = 0; k < 64; ++k) wcol[k] = W[k * 64 + lane];
    const float bias = bvec[lane];
    for (int n = wid0; n < NNODES; n += total_waves) {
        float xv = xin[(n << 6) + lane];
        hrow[wslot][lane] = xv;
        __builtin_amdgcn_wave_barrier();
        float a0 = bias, a1 = 0.0f, a2 = 0.0f, a3 = 0.0f;
#pragma unroll
        for (int g = 0; g < 16; ++g) {
            float4 hv = *(const float4*)&hrow[wslot][g * 4];
            a0 = fmaf(hv.x, wcol[4 * g + 0], a0);
            a1 = fmaf(hv.y, wcol[4 * g + 1], a1);
            a2 = fmaf(hv.z, wcol[4 * g + 2], a2);
            a3 = fmaf(hv.w, wcol[4 * g + 3], a3);
        }
        __builtin_amdgcn_wave_barrier();
        int gi = batch[n];
        atomicMax(&pooled[(gi << 6) + lane], enc_f((a0 + a1) + (a2 + a3)));
    }
}

// ---------- head: MLP + BN + out + log_softmax, single block ----------
__global__ __launch_bounds__(256) void head_k(
    const unsigned* __restrict__ pooled,
    const float* __restrict__ m1w, const float* __restrict__ m1b,
    const float* __restrict__ g1, const float* __restrict__ be1,
    const float* __restrict__ m2w, const float* __restrict__ m2b,
    const float* __restrict__ g2, const float* __restrict__ be2,
    const float* __restrict__ ow, const float* __restrict__ ob,
    float* __restrict__ out) {
    __shared__ float A[NGRAPH * 64];
    __shared__ float B[NGRAPH * 64];
    __shared__ float mu[64], rs[64];
    __shared__ float LG[NGRAPH * 10];
    int t = threadIdx.x;
    for (int i = t; i < NGRAPH * 64; i += 256) {
        float f = dec_f(pooled[i]);
        if (!isfinite(f)) f = 0.0f;   // empty-segment guard
        A[i] = f;
    }
    __syncthreads();
    // ---- mlp1 ----
    for (int i = t; i < NGRAPH * 64; i += 256) {
        int g = i >> 6, j = i & 63;
        float acc = m1b[j];
        for (int k = 0; k < 64; ++k) acc = fmaf(A[(g << 6) + k], m1w[k * 64 + j], acc);
        B[i] = acc;
    }
    __syncthreads();
    if (t < 64) {
        float sm = 0.0f, sq = 0.0f;
        for (int g = 0; g < NGRAPH; ++g) { float z = B[g * 64 + t]; sm += z; sq += z * z; }
        float m = sm * (1.0f / NGRAPH);
        float var = sq * (1.0f / NGRAPH) - m * m;
        mu[t] = m; rs[t] = rsqrtf(var + 1e-5f);
    }
    __syncthreads();
    for (int i = t; i < NGRAPH * 64; i += 256) {
        int j = i & 63;
        float z = fmaf((B[i] - mu[j]) * rs[j], g1[j], be1[j]);
        A[i] = fmaxf(z, 0.0f);
    }
    __syncthreads();
    // ---- mlp2 ----
    for (int i = t; i < NGRAPH * 64; i += 256) {
        int g = i >> 6, j = i & 63;
        float acc = m2b[j];
        for (int k = 0; k < 64; ++k) acc = fmaf(A[(g << 6) + k], m2w[k * 64 + j], acc);
        B[i] = acc;
    }
    __syncthreads();
    if (t < 64) {
        float sm = 0.0f, sq = 0.0f;
        for (int g = 0; g < NGRAPH; ++g) { float z = B[g * 64 + t]; sm += z; sq += z * z; }
        float m = sm * (1.0f / NGRAPH);
        float var = sq * (1.0f / NGRAPH) - m * m;
        mu[t] = m; rs[t] = rsqrtf(var + 1e-5f);
    }
    __syncthreads();
    for (int i = t; i < NGRAPH * 64; i += 256) {
        int j = i & 63;
        float z = fmaf((B[i] - mu[j]) * rs[j], g2[j], be2[j]);
        A[i] = fmaxf(z, 0.0f);
    }
    __syncthreads();
    // ---- out + log_softmax ----
    for (int i = t; i < NGRAPH * 10; i += 256) {
        int g = i / 10, j = i - g * 10;
        float acc = ob[j];
        for (int k = 0; k < 64; ++k) acc = fmaf(A[(g << 6) + k], ow[k * 10 + j], acc);
        LG[i] = acc;
    }
    __syncthreads();
    if (t < NGRAPH) {
        float m = -1e30f;
        for (int j = 0; j < 10; ++j) m = fmaxf(m, LG[t * 10 + j]);
        float s = 0.0f;
        for (int j = 0; j < 10; ++j) s += expf(LG[t * 10 + j] - m);
        float lse = m + logf(s);
        for (int j = 0; j < 10; ++j) out[t * 10 + j] = LG[t * 10 + j] - lse;
    }
}

extern "C" void kernel_launch(void* const* d_in, const int* in_sizes, int n_in,
                              void* d_out, int out_size, void* d_ws, size_t ws_size,
                              hipStream_t stream) {
    const float* pos   = (const float*)d_in[0];
    const int*   eidx  = (const int*)d_in[1];
    const int*   batch = (const int*)d_in[2];
    const float* l0w   = (const float*)d_in[3];
    const float* l0b   = (const float*)d_in[4];
    const float* cw    = (const float*)d_in[5];
    const float* l1w   = (const float*)d_in[6];
    const float* l1b   = (const float*)d_in[7];
    const float* m1w   = (const float*)d_in[8];
    const float* m1b   = (const float*)d_in[9];
    const float* g1    = (const float*)d_in[10];
    const float* b1    = (const float*)d_in[11];
    const float* m2w   = (const float*)d_in[12];
    const float* m2b   = (const float*)d_in[13];
    const float* g2    = (const float*)d_in[14];
    const float* b2    = (const float*)d_in[15];
    const float* ow    = (const float*)d_in[16];
    const float* ob    = (const float*)d_in[17];
    float* out = (float*)d_out;
    const int* src = eidx;
    const int* dst = eidx + NEDGES;

    size_t off = 0;
    auto alloc = [&](size_t bytes) -> void* {
        void* p = (char*)d_ws + off;
        off += (bytes + 255) & ~(size_t)255;
        return p;
    };
    float*    x0     = (float*)alloc((size_t)NNODES * 64 * 4);
    float*    xA     = (float*)alloc((size_t)NNODES * 64 * 4);
    float*    xB     = (float*)alloc((size_t)NNODES * 64 * 4);
    int*      deg    = (int*)alloc((size_t)NNODES * 4);          // reused as cursor
    int*      roff   = (int*)alloc((size_t)(NNODES + 1) * 4);
    const int NBLK   = (NNODES + 255) / 256;                     // 391
    int*      bsum   = (int*)alloc((size_t)NBLK * 4);
    int*      boff   = (int*)alloc((size_t)NBLK * 4);
    int*      csr    = (int*)alloc((size_t)NEDGES * 4);
    unsigned* pooled = (unsigned*)alloc((size_t)NGRAPH * 64 * 4);

    hipMemsetAsync(deg, 0, (size_t)NNODES * 4, stream);
    {
        int total = NNODES * 64;
        lin0_k<<<(total + 255) / 256, 256, 0, stream>>>(pos, l0w, l0b, x0, total);
    }
    hist_k<<<(NEDGES + 255) / 256, 256, 0, stream>>>(dst, deg, NEDGES);
    scan_part_k<<<NBLK, 256, 0, stream>>>(deg, bsum, NNODES);
    scan_mid_k<<<1, 512, 0, stream>>>(bsum, boff, NBLK, roff, NNODES);
    scan_final_k<<<NBLK, 256, 0, stream>>>(deg, boff, roff, NNODES);
    hipMemsetAsync(deg, 0, (size_t)NNODES * 4, stream);          // now cursor
    fill_k<<<(NEDGES + 255) / 256, 256, 0, stream>>>(src, dst, roff, deg, csr, NEDGES);
    init_pool_k<<<(NGRAPH * 64 + 255) / 256, 256, 0, stream>>>(pooled, NGRAPH * 64);

    const int LBLOCKS = 2048;
    const int TW = LBLOCKS * 256 / 64;   // total waves = 8192
    const float* cur = x0;
    for (int l = 0; l < NLAYERS; ++l) {
        float beta = (float)log(0.5 / (double)(l + 1) + 1.0);
        float* nxt = (l & 1) ? xB : xA;
        layer_k<<<LBLOCKS, 256, 0, stream>>>(cur, nxt, x0, cw + (size_t)l * 4096,
                                             roff, csr, beta, TW);
        cur = nxt;
    }
    lin1pool_k<<<LBLOCKS, 256, 0, stream>>>(cur, l1w, l1b, batch, pooled, TW);
    head_k<<<1, 256, 0, stream>>>(pooled, m1w, m1b, g1, b1, m2w, m2b, g2, b2, ow, ob, out);
}

// Round 3
// 1730.668 us; speedup vs baseline: 1.0764x; 1.0764x over previous
//
#include <hip/hip_runtime.h>
#include <math.h>

#define NNODES 100000
#define NEDGES 1200000
#define HD 64
#define NLAYERS 8
#define NGRAPH 100

// ---------- order-preserving float<->uint encoding for atomicMax ----------
__device__ __forceinline__ unsigned enc_f(float f) {
    unsigned b = __float_as_uint(f);
    return (b & 0x80000000u) ? ~b : (b | 0x80000000u);
}
__device__ __forceinline__ float dec_f(unsigned u) {
    unsigned b = (u & 0x80000000u) ? (u ^ 0x80000000u) : ~u;
    return __uint_as_float(b);
}
// sentinel = enc(-inf) = 0x007FFFFF

// ---------- lin0: x0 = relu(pos @ lin0_w + lin0_b) ----------
__global__ void lin0_k(const float* __restrict__ pos, const float* __restrict__ w,
                       const float* __restrict__ b, float* __restrict__ x0, int total) {
    int i = blockIdx.x * blockDim.x + threadIdx.x;
    if (i >= total) return;
    int n = i >> 6, h = i & 63;
    float p0 = pos[n * 3 + 0], p1 = pos[n * 3 + 1], p2 = pos[n * 3 + 2];
    float v = fmaf(p0, w[h], fmaf(p1, w[64 + h], fmaf(p2, w[128 + h], b[h])));
    x0[i] = fmaxf(v, 0.0f);
}

// ---------- CSR build ----------
__global__ void hist_k(const int* __restrict__ dst, int* __restrict__ deg, int E) {
    int e = blockIdx.x * blockDim.x + threadIdx.x;
    if (e < E) atomicAdd(&deg[dst[e]], 1);
}

__global__ void scan_part_k(const int* __restrict__ deg, int* __restrict__ bsum, int n) {
    __shared__ int s[256];
    int t = threadIdx.x;
    int i = blockIdx.x * 256 + t;
    s[t] = (i < n) ? deg[i] : 0;
    __syncthreads();
    for (int off = 128; off > 0; off >>= 1) {
        if (t < off) s[t] += s[t + off];
        __syncthreads();
    }
    if (t == 0) bsum[blockIdx.x] = s[0];
}

__global__ void scan_mid_k(const int* __restrict__ bsum, int* __restrict__ boff,
                           int nblk, int* __restrict__ roff, int n) {
    __shared__ int s[512];
    int t = threadIdx.x;
    int v = (t < nblk) ? bsum[t] : 0;
    s[t] = v;
    __syncthreads();
    for (int off = 1; off < 512; off <<= 1) {
        int u = (t >= off) ? s[t - off] : 0;
        __syncthreads();
        s[t] += u;
        __syncthreads();
    }
    if (t < nblk) boff[t] = s[t] - v;          // exclusive
    if (t == nblk - 1) roff[n] = s[t];         // == E
}

__global__ void scan_final_k(const int* __restrict__ deg, const int* __restrict__ boff,
                             int* __restrict__ roff, int n) {
    __shared__ int s[256];
    int t = threadIdx.x;
    int i = blockIdx.x * 256 + t;
    int v = (i < n) ? deg[i] : 0;
    s[t] = v;
    __syncthreads();
    for (int off = 1; off < 256; off <<= 1) {
        int u = (t >= off) ? s[t - off] : 0;
        __syncthreads();
        s[t] += u;
        __syncthreads();
    }
    if (i < n) roff[i] = boff[blockIdx.x] + s[t] - v;   // exclusive scan
}

__global__ void fill_k(const int* __restrict__ src, const int* __restrict__ dst,
                       const int* __restrict__ roff, int* __restrict__ cursor,
                       int* __restrict__ csr, int E) {
    int e = blockIdx.x * blockDim.x + threadIdx.x;
    if (e < E) {
        int d = dst[e];
        int k = atomicAdd(&cursor[d], 1);
        csr[roff[d] + k] = src[e];
    }
}

__global__ void init_pool_k(unsigned* __restrict__ pooled, int total) {
    int i = blockIdx.x * blockDim.x + threadIdx.x;
    if (i < total) pooled[i] = 0x007FFFFFu;   // enc(-inf)
}

// ---------- fused GCN2 layer: agg + residual + GEMM + relu ----------
// One wave per node. W column held as 32 packed-bf16 VGPRs per lane
// (64 entries, 32 regs) so the kernel fits the 64-VGPR budget of
// 8 waves/SIMD. Identity term (1-beta)*h stays exact f32; bf16 error
// only touches the beta-scaled h@W correction.
__global__ __launch_bounds__(256, 8) void layer_k(
    const float* __restrict__ xin, float* __restrict__ xout,
    const float* __restrict__ x0, const float* __restrict__ W,
    const int* __restrict__ roff, const int* __restrict__ csr,
    float beta, int total_waves) {
    __shared__ __align__(16) float hrow[4][64];
    const int lane  = threadIdx.x & 63;
    const int wslot = threadIdx.x >> 6;
    const int wid0  = (blockIdx.x * blockDim.x + threadIdx.x) >> 6;
    // wp[j] packs {W[2j][lane], W[2j+1][lane]} as 2x bf16 (RNE)
    unsigned wp[32];
#pragma unroll
    for (int j = 0; j < 32; ++j) {
        unsigned lo = __float_as_uint(W[(2 * j + 0) * 64 + lane]);
        unsigned hi = __float_as_uint(W[(2 * j + 1) * 64 + lane]);
        lo = (lo + 0x7fffu + ((lo >> 16) & 1u)) >> 16;            // bf16 in low16
        hi = (hi + 0x7fffu + ((hi >> 16) & 1u)) & 0xffff0000u;    // bf16 in high16
        wp[j] = lo | hi;
    }
    const float omb = 1.0f - beta;
    for (int n = wid0; n < NNODES; n += total_waves) {
        const int beg = roff[n], end = roff[n + 1];
        float x0v = x0[(n << 6) + lane];      // issue early, overlaps gather
        float s0 = 0.0f, s1 = 0.0f, s2 = 0.0f, s3 = 0.0f;
        int i = beg;
        for (; i + 4 <= end; i += 4) {
            int e0 = csr[i + 0], e1 = csr[i + 1], e2 = csr[i + 2], e3 = csr[i + 3];
            s0 += xin[(e0 << 6) + lane];
            s1 += xin[(e1 << 6) + lane];
            s2 += xin[(e2 << 6) + lane];
            s3 += xin[(e3 << 6) + lane];
        }
        for (; i < end; ++i) s0 += xin[(csr[i] << 6) + lane];
        float agg = (s0 + s1) + (s2 + s3);
        float h = fmaf(0.9f, agg, 0.1f * x0v);
        hrow[wslot][lane] = h;
        __builtin_amdgcn_wave_barrier();   // wave-internal LDS RAW; DS in-order per wave
        float a0 = 0.0f, a1 = 0.0f, a2 = 0.0f, a3 = 0.0f;
#pragma unroll
        for (int g = 0; g < 16; ++g) {
            float4 hv = *(const float4*)&hrow[wslot][g * 4];
            unsigned p0 = wp[2 * g + 0], p1 = wp[2 * g + 1];
            a0 = fmaf(hv.x, __uint_as_float(p0 << 16), a0);
            a1 = fmaf(hv.y, __uint_as_float(p0 & 0xffff0000u), a1);
            a2 = fmaf(hv.z, __uint_as_float(p1 << 16), a2);
            a3 = fmaf(hv.w, __uint_as_float(p1 & 0xffff0000u), a3);
        }
        __builtin_amdgcn_wave_barrier();   // keep next iter's write after these reads
        float acc = (a0 + a1) + (a2 + a3);
        float o = fmaf(omb, h, beta * acc);
        xout[(n << 6) + lane] = fmaxf(o, 0.0f);
    }
}

// ---------- lin1 + segment_max pooling fused ----------
__global__ __launch_bounds__(256, 4) void lin1pool_k(
    const float* __restrict__ xin, const float* __restrict__ W,
    const float* __restrict__ bvec, const int* __restrict__ batch,
    unsigned* __restrict__ pooled, int total_waves) {
    __shared__ __align__(16) float hrow[4][64];
    const int lane  = threadIdx.x & 63;
    const int wslot = threadIdx.x >> 6;
    const int wid0  = (blockIdx.x * blockDim.x + threadIdx.x) >> 6;
    float wcol[64];
#pragma unroll
    for (int k = 0; k < 64; ++k) wcol[k] = W[k * 64 + lane];
    const float bias = bvec[lane];
    for (int n = wid0; n < NNODES; n += total_waves) {
        float xv = xin[(n << 6) + lane];
        hrow[wslot][lane] = xv;
        __builtin_amdgcn_wave_barrier();
        float a0 = bias, a1 = 0.0f, a2 = 0.0f, a3 = 0.0f;
#pragma unroll
        for (int g = 0; g < 16; ++g) {
            float4 hv = *(const float4*)&hrow[wslot][g * 4];
            a0 = fmaf(hv.x, wcol[4 * g + 0], a0);
            a1 = fmaf(hv.y, wcol[4 * g + 1], a1);
            a2 = fmaf(hv.z, wcol[4 * g + 2], a2);
            a3 = fmaf(hv.w, wcol[4 * g + 3], a3);
        }
        __builtin_amdgcn_wave_barrier();
        int gi = batch[n];
        atomicMax(&pooled[(gi << 6) + lane], enc_f((a0 + a1) + (a2 + a3)));
    }
}

// ---------- head: MLP + BN + out + log_softmax, single block ----------
__global__ __launch_bounds__(256) void head_k(
    const unsigned* __restrict__ pooled,
    const float* __restrict__ m1w, const float* __restrict__ m1b,
    const float* __restrict__ g1, const float* __restrict__ be1,
    const float* __restrict__ m2w, const float* __restrict__ m2b,
    const float* __restrict__ g2, const float* __restrict__ be2,
    const float* __restrict__ ow, const float* __restrict__ ob,
    float* __restrict__ out) {
    __shared__ float A[NGRAPH * 64];
    __shared__ float B[NGRAPH * 64];
    __shared__ float mu[64], rs[64];
    __shared__ float LG[NGRAPH * 10];
    int t = threadIdx.x;
    for (int i = t; i < NGRAPH * 64; i += 256) {
        float f = dec_f(pooled[i]);
        if (!isfinite(f)) f = 0.0f;   // empty-segment guard
        A[i] = f;
    }
    __syncthreads();
    // ---- mlp1 ----
    for (int i = t; i < NGRAPH * 64; i += 256) {
        int g = i >> 6, j = i & 63;
        float acc = m1b[j];
        for (int k = 0; k < 64; ++k) acc = fmaf(A[(g << 6) + k], m1w[k * 64 + j], acc);
        B[i] = acc;
    }
    __syncthreads();
    if (t < 64) {
        float sm = 0.0f, sq = 0.0f;
        for (int g = 0; g < NGRAPH; ++g) { float z = B[g * 64 + t]; sm += z; sq += z * z; }
        float m = sm * (1.0f / NGRAPH);
        float var = sq * (1.0f / NGRAPH) - m * m;
        mu[t] = m; rs[t] = rsqrtf(var + 1e-5f);
    }
    __syncthreads();
    for (int i = t; i < NGRAPH * 64; i += 256) {
        int j = i & 63;
        float z = fmaf((B[i] - mu[j]) * rs[j], g1[j], be1[j]);
        A[i] = fmaxf(z, 0.0f);
    }
    __syncthreads();
    // ---- mlp2 ----
    for (int i = t; i < NGRAPH * 64; i += 256) {
        int g = i >> 6, j = i & 63;
        float acc = m2b[j];
        for (int k = 0; k < 64; ++k) acc = fmaf(A[(g << 6) + k], m2w[k * 64 + j], acc);
        B[i] = acc;
    }
    __syncthreads();
    if (t < 64) {
        float sm = 0.0f, sq = 0.0f;
        for (int g = 0; g < NGRAPH; ++g) { float z = B[g * 64 + t]; sm += z; sq += z * z; }
        float m = sm * (1.0f / NGRAPH);
        float var = sq * (1.0f / NGRAPH) - m * m;
        mu[t] = m; rs[t] = rsqrtf(var + 1e-5f);
    }
    __syncthreads();
    for (int i = t; i < NGRAPH * 64; i += 256) {
        int j = i & 63;
        float z = fmaf((B[i] - mu[j]) * rs[j], g2[j], be2[j]);
        A[i] = fmaxf(z, 0.0f);
    }
    __syncthreads();
    // ---- out + log_softmax ----
    for (int i = t; i < NGRAPH * 10; i += 256) {
        int g = i / 10, j = i - g * 10;
        float acc = ob[j];
        for (int k = 0; k < 64; ++k) acc = fmaf(A[(g << 6) + k], ow[k * 10 + j], acc);
        LG[i] = acc;
    }
    __syncthreads();
    if (t < NGRAPH) {
        float m = -1e30f;
        for (int j = 0; j < 10; ++j) m = fmaxf(m, LG[t * 10 + j]);
        float s = 0.0f;
        for (int j = 0; j < 10; ++j) s += expf(LG[t * 10 + j] - m);
        float lse = m + logf(s);
        for (int j = 0; j < 10; ++j) out[t * 10 + j] = LG[t * 10 + j] - lse;
    }
}

extern "C" void kernel_launch(void* const* d_in, const int* in_sizes, int n_in,
                              void* d_out, int out_size, void* d_ws, size_t ws_size,
                              hipStream_t stream) {
    const float* pos   = (const float*)d_in[0];
    const int*   eidx  = (const int*)d_in[1];
    const int*   batch = (const int*)d_in[2];
    const float* l0w   = (const float*)d_in[3];
    const float* l0b   = (const float*)d_in[4];
    const float* cw    = (const float*)d_in[5];
    const float* l1w   = (const float*)d_in[6];
    const float* l1b   = (const float*)d_in[7];
    const float* m1w   = (const float*)d_in[8];
    const float* m1b   = (const float*)d_in[9];
    const float* g1    = (const float*)d_in[10];
    const float* b1    = (const float*)d_in[11];
    const float* m2w   = (const float*)d_in[12];
    const float* m2b   = (const float*)d_in[13];
    const float* g2    = (const float*)d_in[14];
    const float* b2    = (const float*)d_in[15];
    const float* ow    = (const float*)d_in[16];
    const float* ob    = (const float*)d_in[17];
    float* out = (float*)d_out;
    const int* src = eidx;
    const int* dst = eidx + NEDGES;

    size_t off = 0;
    auto alloc = [&](size_t bytes) -> void* {
        void* p = (char*)d_ws + off;
        off += (bytes + 255) & ~(size_t)255;
        return p;
    };
    float*    x0     = (float*)alloc((size_t)NNODES * 64 * 4);
    float*    xA     = (float*)alloc((size_t)NNODES * 64 * 4);
    float*    xB     = (float*)alloc((size_t)NNODES * 64 * 4);
    int*      deg    = (int*)alloc((size_t)NNODES * 4);          // reused as cursor
    int*      roff   = (int*)alloc((size_t)(NNODES + 1) * 4);
    const int NBLK   = (NNODES + 255) / 256;                     // 391
    int*      bsum   = (int*)alloc((size_t)NBLK * 4);
    int*      boff   = (int*)alloc((size_t)NBLK * 4);
    int*      csr    = (int*)alloc((size_t)NEDGES * 4);
    unsigned* pooled = (unsigned*)alloc((size_t)NGRAPH * 64 * 4);

    hipMemsetAsync(deg, 0, (size_t)NNODES * 4, stream);
    {
        int total = NNODES * 64;
        lin0_k<<<(total + 255) / 256, 256, 0, stream>>>(pos, l0w, l0b, x0, total);
    }
    hist_k<<<(NEDGES + 255) / 256, 256, 0, stream>>>(dst, deg, NEDGES);
    scan_part_k<<<NBLK, 256, 0, stream>>>(deg, bsum, NNODES);
    scan_mid_k<<<1, 512, 0, stream>>>(bsum, boff, NBLK, roff, NNODES);
    scan_final_k<<<NBLK, 256, 0, stream>>>(deg, boff, roff, NNODES);
    hipMemsetAsync(deg, 0, (size_t)NNODES * 4, stream);          // now cursor
    fill_k<<<(NEDGES + 255) / 256, 256, 0, stream>>>(src, dst, roff, deg, csr, NEDGES);
    init_pool_k<<<(NGRAPH * 64 + 255) / 256, 256, 0, stream>>>(pooled, NGRAPH * 64);

    const int LBLOCKS = 2048;
    const int TW = LBLOCKS * 256 / 64;   // total waves = 8192
    const float* cur = x0;
    for (int l = 0; l < NLAYERS; ++l) {
        float beta = (float)log(0.5 / (double)(l + 1) + 1.0);
        float* nxt = (l & 1) ? xB : xA;
        layer_k<<<LBLOCKS, 256, 0, stream>>>(cur, nxt, x0, cw + (size_t)l * 4096,
                                             roff, csr, beta, TW);
        cur = nxt;
    }
    lin1pool_k<<<LBLOCKS, 256, 0, stream>>>(cur, l1w, l1b, batch, pooled, TW);
    head_k<<<1, 256, 0, stream>>>(pooled, m1w, m1b, g1, b1, m2w, m2b, g2, b2, ow, ob, out);
}

// Round 4
// 743.372 us; speedup vs baseline: 2.5061x; 2.3281x over previous
//
#include <hip/hip_runtime.h>
#include <math.h>

#define NNODES 100000
#define NEDGES 1200000
#define HD 64
#define NLAYERS 8
#define NGRAPH 100

// ---------- order-preserving float<->uint encoding for atomicMax ----------
__device__ __forceinline__ unsigned enc_f(float f) {
    unsigned b = __float_as_uint(f);
    return (b & 0x80000000u) ? ~b : (b | 0x80000000u);
}
__device__ __forceinline__ float dec_f(unsigned u) {
    unsigned b = (u & 0x80000000u) ? (u ^ 0x80000000u) : ~u;
    return __uint_as_float(b);
}
// sentinel = enc(-inf) = 0x007FFFFF

// ---------- lin0: x0 = relu(pos @ lin0_w + lin0_b) ----------
__global__ void lin0_k(const float* __restrict__ pos, const float* __restrict__ w,
                       const float* __restrict__ b, float* __restrict__ x0, int total) {
    int i = blockIdx.x * blockDim.x + threadIdx.x;
    if (i >= total) return;
    int n = i >> 6, h = i & 63;
    float p0 = pos[n * 3 + 0], p1 = pos[n * 3 + 1], p2 = pos[n * 3 + 2];
    float v = fmaf(p0, w[h], fmaf(p1, w[64 + h], fmaf(p2, w[128 + h], b[h])));
    x0[i] = fmaxf(v, 0.0f);
}

// ---------- CSR build ----------
__global__ void hist_k(const int* __restrict__ dst, int* __restrict__ deg, int E) {
    int e = blockIdx.x * blockDim.x + threadIdx.x;
    if (e < E) atomicAdd(&deg[dst[e]], 1);
}

__global__ void scan_part_k(const int* __restrict__ deg, int* __restrict__ bsum, int n) {
    __shared__ int s[256];
    int t = threadIdx.x;
    int i = blockIdx.x * 256 + t;
    s[t] = (i < n) ? deg[i] : 0;
    __syncthreads();
    for (int off = 128; off > 0; off >>= 1) {
        if (t < off) s[t] += s[t + off];
        __syncthreads();
    }
    if (t == 0) bsum[blockIdx.x] = s[0];
}

__global__ void scan_mid_k(const int* __restrict__ bsum, int* __restrict__ boff,
                           int nblk, int* __restrict__ roff, int n) {
    __shared__ int s[512];
    int t = threadIdx.x;
    int v = (t < nblk) ? bsum[t] : 0;
    s[t] = v;
    __syncthreads();
    for (int off = 1; off < 512; off <<= 1) {
        int u = (t >= off) ? s[t - off] : 0;
        __syncthreads();
        s[t] += u;
        __syncthreads();
    }
    if (t < nblk) boff[t] = s[t] - v;          // exclusive
    if (t == nblk - 1) roff[n] = s[t];         // == E
}

__global__ void scan_final_k(const int* __restrict__ deg, const int* __restrict__ boff,
                             int* __restrict__ roff, int n) {
    __shared__ int s[256];
    int t = threadIdx.x;
    int i = blockIdx.x * 256 + t;
    int v = (i < n) ? deg[i] : 0;
    s[t] = v;
    __syncthreads();
    for (int off = 1; off < 256; off <<= 1) {
        int u = (t >= off) ? s[t - off] : 0;
        __syncthreads();
        s[t] += u;
        __syncthreads();
    }
    if (i < n) roff[i] = boff[blockIdx.x] + s[t] - v;   // exclusive scan
}

__global__ void fill_k(const int* __restrict__ src, const int* __restrict__ dst,
                       const int* __restrict__ roff, int* __restrict__ cursor,
                       int* __restrict__ csr, int E) {
    int e = blockIdx.x * blockDim.x + threadIdx.x;
    if (e < E) {
        int d = dst[e];
        int k = atomicAdd(&cursor[d], 1);
        csr[roff[d] + k] = src[e];
    }
}

__global__ void init_pool_k(unsigned* __restrict__ pooled, int total) {
    int i = blockIdx.x * blockDim.x + threadIdx.x;
    if (i < total) pooled[i] = 0x007FFFFFu;   // enc(-inf)
}

// ---------- fused GCN2 layer: agg + residual + GEMM + relu ----------
// One wave per node. Folded matrix M = (1-beta)*I + beta*W lives in LDS
// (shared per block, exact f32), stored as swizzled M^T so the per-lane
// column read is a conflict-free ds_read_b128:
//   MT float idx = j*64 + ((q ^ (j&15))<<2) + (k&3)   where q=k>>2, j=col
// Lane register pressure ~45 -> true 8 waves/SIMD, no spill.
__global__ __launch_bounds__(256, 8) void layer_k(
    const float* __restrict__ xin, float* __restrict__ xout,
    const float* __restrict__ x0, const float* __restrict__ W,
    const int* __restrict__ roff, const int* __restrict__ csr,
    float beta, int total_waves) {
    __shared__ __align__(16) float MT[64 * 64];
    __shared__ __align__(16) float hrow[4][64];
    const int tid   = threadIdx.x;
    const int lane  = tid & 63;
    const int wslot = tid >> 6;
    const float omb = 1.0f - beta;
    // build swizzled M^T (coalesced W read: idx = k*64 + j)
    for (int idx = tid; idx < 4096; idx += 256) {
        int k = idx >> 6, j = idx & 63;
        float m = beta * W[idx];
        if (k == j) m += omb;
        int slot = (k >> 2) ^ (j & 15);
        MT[j * 64 + slot * 4 + (k & 3)] = m;
    }
    __syncthreads();
    const int wid0 = (blockIdx.x * blockDim.x + tid) >> 6;
    for (int n = wid0; n < NNODES; n += total_waves) {
        const int beg = roff[n], end = roff[n + 1];
        float x0v = x0[(n << 6) + lane];      // issue early, overlaps gather
        float s0 = 0.0f, s1 = 0.0f, s2 = 0.0f, s3 = 0.0f;
        int i = beg;
        for (; i + 4 <= end; i += 4) {
            int e0 = csr[i + 0], e1 = csr[i + 1], e2 = csr[i + 2], e3 = csr[i + 3];
            s0 += xin[(e0 << 6) + lane];
            s1 += xin[(e1 << 6) + lane];
            s2 += xin[(e2 << 6) + lane];
            s3 += xin[(e3 << 6) + lane];
        }
        for (; i < end; ++i) s0 += xin[(csr[i] << 6) + lane];
        float agg = (s0 + s1) + (s2 + s3);
        float h = fmaf(0.9f, agg, 0.1f * x0v);
        hrow[wslot][lane] = h;
        __builtin_amdgcn_wave_barrier();   // wave-internal LDS RAW; DS in-order per wave
        float a0 = 0.0f, a1 = 0.0f, a2 = 0.0f, a3 = 0.0f;
#pragma unroll
        for (int g = 0; g < 16; ++g) {
            float4 hv = *(const float4*)&hrow[wslot][g * 4];                  // broadcast
            float4 mv = *(const float4*)&MT[(lane << 6) + ((g ^ (lane & 15)) << 2)];
            a0 = fmaf(hv.x, mv.x, a0);
            a1 = fmaf(hv.y, mv.y, a1);
            a2 = fmaf(hv.z, mv.z, a2);
            a3 = fmaf(hv.w, mv.w, a3);
        }
        __builtin_amdgcn_wave_barrier();   // keep next iter's write after these reads
        float o = (a0 + a1) + (a2 + a3);   // identity already folded into M
        xout[(n << 6) + lane] = fmaxf(o, 0.0f);
    }
}

// ---------- lin1 + segment_max pooling fused (same LDS-W scheme) ----------
__global__ __launch_bounds__(256, 8) void lin1pool_k(
    const float* __restrict__ xin, const float* __restrict__ W,
    const float* __restrict__ bvec, const int* __restrict__ batch,
    unsigned* __restrict__ pooled, int total_waves) {
    __shared__ __align__(16) float MT[64 * 64];
    __shared__ __align__(16) float hrow[4][64];
    const int tid   = threadIdx.x;
    const int lane  = tid & 63;
    const int wslot = tid >> 6;
    for (int idx = tid; idx < 4096; idx += 256) {
        int k = idx >> 6, j = idx & 63;
        int slot = (k >> 2) ^ (j & 15);
        MT[j * 64 + slot * 4 + (k & 3)] = W[idx];
    }
    __syncthreads();
    const float bias = bvec[lane];
    const int wid0 = (blockIdx.x * blockDim.x + tid) >> 6;
    for (int n = wid0; n < NNODES; n += total_waves) {
        float xv = xin[(n << 6) + lane];
        int gi = batch[n];
        hrow[wslot][lane] = xv;
        __builtin_amdgcn_wave_barrier();
        float a0 = bias, a1 = 0.0f, a2 = 0.0f, a3 = 0.0f;
#pragma unroll
        for (int g = 0; g < 16; ++g) {
            float4 hv = *(const float4*)&hrow[wslot][g * 4];
            float4 mv = *(const float4*)&MT[(lane << 6) + ((g ^ (lane & 15)) << 2)];
            a0 = fmaf(hv.x, mv.x, a0);
            a1 = fmaf(hv.y, mv.y, a1);
            a2 = fmaf(hv.z, mv.z, a2);
            a3 = fmaf(hv.w, mv.w, a3);
        }
        __builtin_amdgcn_wave_barrier();
        atomicMax(&pooled[(gi << 6) + lane], enc_f((a0 + a1) + (a2 + a3)));
    }
}

// ---------- head: MLP + BN + out + log_softmax, single block ----------
__global__ __launch_bounds__(256) void head_k(
    const unsigned* __restrict__ pooled,
    const float* __restrict__ m1w, const float* __restrict__ m1b,
    const float* __restrict__ g1, const float* __restrict__ be1,
    const float* __restrict__ m2w, const float* __restrict__ m2b,
    const float* __restrict__ g2, const float* __restrict__ be2,
    const float* __restrict__ ow, const float* __restrict__ ob,
    float* __restrict__ out) {
    __shared__ float A[NGRAPH * 64];
    __shared__ float B[NGRAPH * 64];
    __shared__ float mu[64], rs[64];
    __shared__ float LG[NGRAPH * 10];
    int t = threadIdx.x;
    for (int i = t; i < NGRAPH * 64; i += 256) {
        float f = dec_f(pooled[i]);
        if (!isfinite(f)) f = 0.0f;   // empty-segment guard
        A[i] = f;
    }
    __syncthreads();
    // ---- mlp1 ----
    for (int i = t; i < NGRAPH * 64; i += 256) {
        int g = i >> 6, j = i & 63;
        float acc = m1b[j];
        for (int k = 0; k < 64; ++k) acc = fmaf(A[(g << 6) + k], m1w[k * 64 + j], acc);
        B[i] = acc;
    }
    __syncthreads();
    if (t < 64) {
        float sm = 0.0f, sq = 0.0f;
        for (int g = 0; g < NGRAPH; ++g) { float z = B[g * 64 + t]; sm += z; sq += z * z; }
        float m = sm * (1.0f / NGRAPH);
        float var = sq * (1.0f / NGRAPH) - m * m;
        mu[t] = m; rs[t] = rsqrtf(var + 1e-5f);
    }
    __syncthreads();
    for (int i = t; i < NGRAPH * 64; i += 256) {
        int j = i & 63;
        float z = fmaf((B[i] - mu[j]) * rs[j], g1[j], be1[j]);
        A[i] = fmaxf(z, 0.0f);
    }
    __syncthreads();
    // ---- mlp2 ----
    for (int i = t; i < NGRAPH * 64; i += 256) {
        int g = i >> 6, j = i & 63;
        float acc = m2b[j];
        for (int k = 0; k < 64; ++k) acc = fmaf(A[(g << 6) + k], m2w[k * 64 + j], acc);
        B[i] = acc;
    }
    __syncthreads();
    if (t < 64) {
        float sm = 0.0f, sq = 0.0f;
        for (int g = 0; g < NGRAPH; ++g) { float z = B[g * 64 + t]; sm += z; sq += z * z; }
        float m = sm * (1.0f / NGRAPH);
        float var = sq * (1.0f / NGRAPH) - m * m;
        mu[t] = m; rs[t] = rsqrtf(var + 1e-5f);
    }
    __syncthreads();
    for (int i = t; i < NGRAPH * 64; i += 256) {
        int j = i & 63;
        float z = fmaf((B[i] - mu[j]) * rs[j], g2[j], be2[j]);
        A[i] = fmaxf(z, 0.0f);
    }
    __syncthreads();
    // ---- out + log_softmax ----
    for (int i = t; i < NGRAPH * 10; i += 256) {
        int g = i / 10, j = i - g * 10;
        float acc = ob[j];
        for (int k = 0; k < 64; ++k) acc = fmaf(A[(g << 6) + k], ow[k * 10 + j], acc);
        LG[i] = acc;
    }
    __syncthreads();
    if (t < NGRAPH) {
        float m = -1e30f;
        for (int j = 0; j < 10; ++j) m = fmaxf(m, LG[t * 10 + j]);
        float s = 0.0f;
        for (int j = 0; j < 10; ++j) s += expf(LG[t * 10 + j] - m);
        float lse = m + logf(s);
        for (int j = 0; j < 10; ++j) out[t * 10 + j] = LG[t * 10 + j] - lse;
    }
}

extern "C" void kernel_launch(void* const* d_in, const int* in_sizes, int n_in,
                              void* d_out, int out_size, void* d_ws, size_t ws_size,
                              hipStream_t stream) {
    const float* pos   = (const float*)d_in[0];
    const int*   eidx  = (const int*)d_in[1];
    const int*   batch = (const int*)d_in[2];
    const float* l0w   = (const float*)d_in[3];
    const float* l0b   = (const float*)d_in[4];
    const float* cw    = (const float*)d_in[5];
    const float* l1w   = (const float*)d_in[6];
    const float* l1b   = (const float*)d_in[7];
    const float* m1w   = (const float*)d_in[8];
    const float* m1b   = (const float*)d_in[9];
    const float* g1    = (const float*)d_in[10];
    const float* b1    = (const float*)d_in[11];
    const float* m2w   = (const float*)d_in[12];
    const float* m2b   = (const float*)d_in[13];
    const float* g2    = (const float*)d_in[14];
    const float* b2    = (const float*)d_in[15];
    const float* ow    = (const float*)d_in[16];
    const float* ob    = (const float*)d_in[17];
    float* out = (float*)d_out;
    const int* src = eidx;
    const int* dst = eidx + NEDGES;

    size_t off = 0;
    auto alloc = [&](size_t bytes) -> void* {
        void* p = (char*)d_ws + off;
        off += (bytes + 255) & ~(size_t)255;
        return p;
    };
    float*    x0     = (float*)alloc((size_t)NNODES * 64 * 4);
    float*    xA     = (float*)alloc((size_t)NNODES * 64 * 4);
    float*    xB     = (float*)alloc((size_t)NNODES * 64 * 4);
    int*      deg    = (int*)alloc((size_t)NNODES * 4);          // reused as cursor
    int*      roff   = (int*)alloc((size_t)(NNODES + 1) * 4);
    const int NBLK   = (NNODES + 255) / 256;                     // 391
    int*      bsum   = (int*)alloc((size_t)NBLK * 4);
    int*      boff   = (int*)alloc((size_t)NBLK * 4);
    int*      csr    = (int*)alloc((size_t)NEDGES * 4);
    unsigned* pooled = (unsigned*)alloc((size_t)NGRAPH * 64 * 4);

    hipMemsetAsync(deg, 0, (size_t)NNODES * 4, stream);
    {
        int total = NNODES * 64;
        lin0_k<<<(total + 255) / 256, 256, 0, stream>>>(pos, l0w, l0b, x0, total);
    }
    hist_k<<<(NEDGES + 255) / 256, 256, 0, stream>>>(dst, deg, NEDGES);
    scan_part_k<<<NBLK, 256, 0, stream>>>(deg, bsum, NNODES);
    scan_mid_k<<<1, 512, 0, stream>>>(bsum, boff, NBLK, roff, NNODES);
    scan_final_k<<<NBLK, 256, 0, stream>>>(deg, boff, roff, NNODES);
    hipMemsetAsync(deg, 0, (size_t)NNODES * 4, stream);          // now cursor
    fill_k<<<(NEDGES + 255) / 256, 256, 0, stream>>>(src, dst, roff, deg, csr, NEDGES);
    init_pool_k<<<(NGRAPH * 64 + 255) / 256, 256, 0, stream>>>(pooled, NGRAPH * 64);

    const int LBLOCKS = 2048;
    const int TW = LBLOCKS * 256 / 64;   // total waves = 8192
    const float* cur = x0;
    for (int l = 0; l < NLAYERS; ++l) {
        float beta = (float)log(0.5 / (double)(l + 1) + 1.0);
        float* nxt = (l & 1) ? xB : xA;
        layer_k<<<LBLOCKS, 256, 0, stream>>>(cur, nxt, x0, cw + (size_t)l * 4096,
                                             roff, csr, beta, TW);
        cur = nxt;
    }
    lin1pool_k<<<LBLOCKS, 256, 0, stream>>>(cur, l1w, l1b, batch, pooled, TW);
    head_k<<<1, 256, 0, stream>>>(pooled, m1w, m1b, g1, b1, m2w, m2b, g2, b2, ow, ob, out);
}